// Round 1
// baseline (1049.129 us; speedup 1.0000x reference)
//
#include <hip/hip_runtime.h>

using uint = unsigned int;
using ushort = unsigned short;
using f32x4 = __attribute__((ext_vector_type(4))) float;
using bf16x8 = __attribute__((ext_vector_type(8))) short;

// ---------- helpers ----------
__device__ __forceinline__ ushort f2bf(float x) {
  uint b = __float_as_uint(x);
  return (ushort)((b + 0x7FFFu + ((b >> 16) & 1u)) >> 16);
}
__device__ __forceinline__ float bf2f(ushort u) { return __uint_as_float(((uint)u) << 16); }

__device__ __forceinline__ void gload16(const void* g, void* l) {
  __builtin_amdgcn_global_load_lds((const __attribute__((address_space(1))) void*)g,
                                   (__attribute__((address_space(3))) void*)l, 16, 0, 0);
}

struct __align__(8) U4 { ushort x, y, z, w; };

// ---------- transpose + bf16 split convert: src (R,C) f32 -> out (C rows, ldo cols), zero for r>=R ----------
__device__ __forceinline__ void convT_impl(const float* src, ushort* oh, ushort* ol, int R, int C, int ldo) {
  const int r0 = blockIdx.x * 32, c0 = blockIdx.y * 32;
  if (r0 >= ldo || c0 >= C) return;
  __shared__ float tile[32][33];
  const int tx = threadIdx.x & 31, ty = threadIdx.x >> 5;
#pragma unroll
  for (int j = 0; j < 4; ++j) {
    const int r = r0 + ty + j * 8;
    tile[ty + j * 8][tx] = (r < R) ? src[(size_t)r * C + c0 + tx] : 0.f;
  }
  __syncthreads();
#pragma unroll
  for (int j = 0; j < 4; ++j) {
    const int c = c0 + ty + j * 8;
    const int r = r0 + tx;
    const float v = tile[tx][ty + j * 8];
    const ushort hb = f2bf(v);
    oh[(size_t)c * ldo + r] = hb;
    if (ol) ol[(size_t)c * ldo + r] = f2bf(v - bf2f(hb));
  }
}

struct ConvBig { const float* s[5]; ushort* oh[5]; ushort* ol[5]; };
__global__ void conv_big_k(ConvBig a) {
  const int z = blockIdx.z;
  convT_impl(a.s[z], a.oh[z], a.ol[z], 1024, 1024, 1024);
}

struct ConvSmall { const float* s[8]; ushort* oh[8]; int R[8]; int C[8]; int ldo[8]; };
__global__ void conv_small_k(ConvSmall a) {
  const int z = blockIdx.z;
  convT_impl(a.s[z], a.oh[z], nullptr, a.R[z], a.C[z], a.ldo[z]);
}

// ---------- token-shift mix for xxx = x + (prev - x)*time_maa_x  -> bf16 (hi only) ----------
__global__ void mixx_k(const float* __restrict__ x, const float* __restrict__ sh,
                       const float* __restrict__ maa, ushort* __restrict__ xh) {
  const size_t i = ((size_t)blockIdx.x * 256 + threadIdx.x) * 4;
  const size_t row = i >> 10;
  const int col = (int)(i & 1023);
  const float4 xv = *(const float4*)(x + i);
  const float4 pv = (row < 4) ? *(const float4*)(sh + i) : *(const float4*)(x + i - 4096);
  const float4 mv = *(const float4*)(maa + col);
  U4 o;
  o.x = f2bf(xv.x + (pv.x - xv.x) * mv.x);
  o.y = f2bf(xv.y + (pv.y - xv.y) * mv.y);
  o.z = f2bf(xv.z + (pv.z - xv.z) * mv.z);
  o.w = f2bf(xv.w + (pv.w - xv.w) * mv.w);
  *(U4*)(xh + i) = o;
}

// ---------- GEMM: C(M=4096, N) = A(M,K) @ B(K,N), A row-major bf16 h/l, B given as B^T (N,K) bf16 h/l ----------
// split=1: acc = Ah*Bh + Ah*Bl + Al*Bh (fp32-grade).  BM=BN=128, BK=64, 256 thr (4 waves, 2x2 quadrants).
// LDS tiles [128][64] bf16, XOR swizzle (byte ^= (row&7)<<4) applied on the GLOBAL source address
// (global_load_lds dest must be linear), inverse applied on ds_read side.
struct GemmP {
  const ushort *Ah, *Al, *Bh, *Bl;
  void *out0, *out1;
  const float *aux0, *aux1, *aux2;
  int lda, ldb, M, N, K, epi, split;
};

__device__ __forceinline__ bf16x8 fragld(const ushort* smbase, int byteOff, int rb, int ks, int l) {
  const int row = rb + (l & 15);
  const int kb = (ks << 6) | (((l >> 4) & 3) << 4);
  const int off = byteOff + row * 128 + (kb ^ ((row & 7) << 4));
  return *(const bf16x8*)((const char*)smbase + off);
}

__global__ __launch_bounds__(256, 2) void gemm_k(GemmP p) {
  __shared__ __align__(16) ushort sm[32768];  // 64KB: Ah | Bh | Al | Bl, 16KB each
  const int t = threadIdx.x;
  const int l = t & 63, wid = t >> 6;
  const int wm = wid >> 1, wn = wid & 1;
  const int bm = blockIdx.x, bn = blockIdx.y;

  f32x4 acc[4][4];
#pragma unroll
  for (int i = 0; i < 4; ++i)
#pragma unroll
    for (int j = 0; j < 4; ++j) acc[i][j] = (f32x4){0.f, 0.f, 0.f, 0.f};

  const int srow = t >> 3;         // 0..31
  const int skb = (t & 7) << 4;    // 0..112
  const int KT = (p.K + 63) >> 6;

  for (int kt = 0; kt < KT; ++kt) {
    const int k0 = kt << 6;
    __syncthreads();
#pragma unroll
    for (int j = 0; j < 4; ++j) {
      const int row = srow + j * 32;
      const int srcK = k0 + ((skb ^ ((row & 7) << 4)) >> 1);
      gload16(p.Ah + (size_t)(bm * 128 + row) * p.lda + srcK, (char*)sm + row * 128 + skb);
      gload16(p.Bh + (size_t)(bn * 128 + row) * p.ldb + srcK, (char*)sm + 16384 + row * 128 + skb);
    }
    if (p.split) {
#pragma unroll
      for (int j = 0; j < 4; ++j) {
        const int row = srow + j * 32;
        const int srcK = k0 + ((skb ^ ((row & 7) << 4)) >> 1);
        gload16(p.Al + (size_t)(bm * 128 + row) * p.lda + srcK, (char*)sm + 32768 + row * 128 + skb);
        gload16(p.Bl + (size_t)(bn * 128 + row) * p.ldb + srcK, (char*)sm + 49152 + row * 128 + skb);
      }
    }
    __syncthreads();
#pragma unroll
    for (int ks = 0; ks < 2; ++ks) {
      bf16x8 ah[4], bh[4];
#pragma unroll
      for (int f = 0; f < 4; ++f) {
        ah[f] = fragld(sm, 0, wm * 64 + f * 16, ks, l);
        bh[f] = fragld(sm, 16384, wn * 64 + f * 16, ks, l);
      }
      if (p.split) {
        bf16x8 al[4], bl[4];
#pragma unroll
        for (int f = 0; f < 4; ++f) {
          al[f] = fragld(sm, 32768, wm * 64 + f * 16, ks, l);
          bl[f] = fragld(sm, 49152, wn * 64 + f * 16, ks, l);
        }
#pragma unroll
        for (int mf = 0; mf < 4; ++mf)
#pragma unroll
          for (int nf = 0; nf < 4; ++nf) {
            acc[mf][nf] = __builtin_amdgcn_mfma_f32_16x16x32_bf16(ah[mf], bh[nf], acc[mf][nf], 0, 0, 0);
            acc[mf][nf] = __builtin_amdgcn_mfma_f32_16x16x32_bf16(ah[mf], bl[nf], acc[mf][nf], 0, 0, 0);
            acc[mf][nf] = __builtin_amdgcn_mfma_f32_16x16x32_bf16(al[mf], bh[nf], acc[mf][nf], 0, 0, 0);
          }
      } else {
#pragma unroll
        for (int mf = 0; mf < 4; ++mf)
#pragma unroll
          for (int nf = 0; nf < 4; ++nf)
            acc[mf][nf] = __builtin_amdgcn_mfma_f32_16x16x32_bf16(ah[mf], bh[nf], acc[mf][nf], 0, 0, 0);
      }
    }
  }

  // epilogue: D row = (l>>4)*4 + reg, col = l&15 (m89-verified)
  const int rb0 = bm * 128 + wm * 64 + ((l >> 4) << 2);
  const int cb0 = bn * 128 + wn * 64 + (l & 15);
#pragma unroll
  for (int mf = 0; mf < 4; ++mf) {
#pragma unroll
    for (int nf = 0; nf < 4; ++nf) {
      const int col = cb0 + nf * 16;
      if (col >= p.N) continue;
#pragma unroll
      for (int jj = 0; jj < 4; ++jj) {
        const int row = rb0 + mf * 16 + jj;
        const float v = acc[mf][nf][jj];
        const size_t o = (size_t)row * p.N + col;
        if (p.epi == 0) {
          ((float*)p.out0)[o] = v;
        } else if (p.epi == 1) {           // tanh -> bf16 (hi)
          ((ushort*)p.out0)[o] = f2bf(tanhf(v));
        } else if (p.epi == 2) {           // swish -> f32
          ((float*)p.out0)[o] = v / (1.f + expf(-v));
        } else if (p.epi == 3) {           // token-shift mix -> bf16 hi/lo
          const float x = p.aux0[(size_t)row * 1024 + col];
          const float pv = (row < 4) ? p.aux1[(size_t)row * 1024 + col]
                                     : p.aux0[(size_t)(row - 4) * 1024 + col];
          const float xi = x + (pv - x) * (p.aux2[col] + v);
          const ushort hb = f2bf(xi);
          ((ushort*)p.out0)[o] = hb;
          ((ushort*)p.out1)[o] = f2bf(xi - bf2f(hb));
        } else {                            // epi==4: w = exp(-exp(acc + time_decay[c])) -> f32
          ((float*)p.out0)[o] = expf(-expf(v + p.aux0[col]));
        }
      }
    }
  }
}

// ---------- WKV6 scan: lane owns 2 state rows (n, n+1) of one column m; 32-lane shuffle reduce ----------
__global__ __launch_bounds__(256) void wkv_k(const float* __restrict__ rf, const float* __restrict__ kf,
                                             const float* __restrict__ vf, const float* __restrict__ wf,
                                             const float* __restrict__ tf, const float* __restrict__ st0,
                                             float* __restrict__ so, float* __restrict__ stO) {
  const int bh = blockIdx.x >> 3, mg = blockIdx.x & 7;
  const int wid = threadIdx.x >> 6, l = threadIdx.x & 63;
  const int m = mg * 8 + wid * 2 + (l >> 5);
  const int n = (l & 31) << 1;
  const int b = bh >> 4, h = bh & 15;
  const size_t sOff = ((size_t)bh * 64 + n) * 64 + m;
  float s0 = st0[sOff], s1 = st0[sOff + 64];
  const float u0 = tf[h * 64 + n], u1 = tf[h * 64 + n + 1];
  size_t cur = (size_t)b * 1024 + h * 64;
  float2 r2 = *(const float2*)(rf + cur + n);
  float2 k2 = *(const float2*)(kf + cur + n);
  float2 w2 = *(const float2*)(wf + cur + n);
  float vm = vf[cur + m];
  for (int t = 0; t < 1024; ++t) {
    float2 nr = {0.f, 0.f}, nk = {0.f, 0.f}, nw = {0.f, 0.f};
    float nv = 0.f;
    if (t < 1023) {
      const size_t nx = cur + 4096;
      nr = *(const float2*)(rf + nx + n);
      nk = *(const float2*)(kf + nx + n);
      nw = *(const float2*)(wf + nx + n);
      nv = vf[nx + m];
    }
    const float kv0 = k2.x * vm, kv1 = k2.y * vm;
    float pr = r2.x * fmaf(u0, kv0, s0) + r2.y * fmaf(u1, kv1, s1);
    s0 = fmaf(w2.x, s0, kv0);
    s1 = fmaf(w2.y, s1, kv1);
    pr += __shfl_xor(pr, 1);
    pr += __shfl_xor(pr, 2);
    pr += __shfl_xor(pr, 4);
    pr += __shfl_xor(pr, 8);
    pr += __shfl_xor(pr, 16);
    if ((l & 31) == 0) so[cur + m] = pr;
    cur += 4096;
    r2 = nr; k2 = nk; w2 = nw; vm = nv;
  }
  stO[sOff] = s0;
  stO[sOff + 64] = s1;
}

// ---------- GroupNorm over (B, N) per (t,h), fused *g gate, -> bf16 hi/lo ----------
__global__ __launch_bounds__(256) void gn_k(const float* __restrict__ so, const float* __restrict__ gf,
                                            const float* __restrict__ sc, const float* __restrict__ bi,
                                            ushort* __restrict__ yh, ushort* __restrict__ yl) {
  const int tdx = threadIdx.x;
  const int b = tdx >> 6, n = tdx & 63;
  const int t = blockIdx.x, h = blockIdx.y;
  const size_t idx = (size_t)t * 4096 + (size_t)b * 1024 + h * 64 + n;
  const float v = so[idx];
  float s = v, s2 = v * v;
#pragma unroll
  for (int off = 1; off < 64; off <<= 1) {
    s += __shfl_xor(s, off);
    s2 += __shfl_xor(s2, off);
  }
  __shared__ float ps[4], ps2[4];
  if ((tdx & 63) == 0) { ps[b] = s; ps2[b] = s2; }
  __syncthreads();
  const float S = ps[0] + ps[1] + ps[2] + ps[3];
  const float S2 = ps2[0] + ps2[1] + ps2[2] + ps2[3];
  const float mean = S * (1.f / 256.f);
  const float var = S2 * (1.f / 256.f) - mean * mean;
  const float inv = rsqrtf(var + 6.4e-4f);  // eps = 1e-5 * 8^2
  const int c = h * 64 + n;
  float y = (v - mean) * inv * sc[c] + bi[c];
  y *= gf[idx];
  const ushort hb = f2bf(y);
  yh[idx] = hb;
  yl[idx] = f2bf(y - bf2f(hb));
}

// ---------- host ----------
extern "C" void kernel_launch(void* const* d_in, const int* in_sizes, int n_in,
                              void* d_out, int out_size, void* d_ws, size_t ws_size,
                              hipStream_t stream) {
  const float* inp = (const float*)d_in[0];
  const float* shifted = (const float*)d_in[1];
  const float* st0 = (const float*)d_in[2];
  const float* maa_x = (const float*)d_in[3];
  const float* maa[5] = {(const float*)d_in[4], (const float*)d_in[5], (const float*)d_in[6],
                         (const float*)d_in[7], (const float*)d_in[8]};  // w,k,v,r,g
  const float* w1 = (const float*)d_in[9];
  const float* w2 = (const float*)d_in[10];
  const float* W[5] = {(const float*)d_in[11], (const float*)d_in[12], (const float*)d_in[13],
                       (const float*)d_in[14], (const float*)d_in[15]};  // Wr Wk Wv Wg Wo
  const float* tdw1 = (const float*)d_in[16];
  const float* tdw2 = (const float*)d_in[17];
  const float* tdec = (const float*)d_in[18];
  const float* tf = (const float*)d_in[19];
  const float* gsc = (const float*)d_in[20];
  const float* gbi = (const float*)d_in[21];
  (void)in_sizes; (void)n_in; (void)out_size; (void)ws_size;

  char* ws = (char*)d_ws;
  size_t cur = 0;
  auto alloc = [&](size_t bytes) { char* r = ws + cur; cur += (bytes + 255) & ~(size_t)255; return r; };
  ushort *WT_h[5], *WT_l[5];
  for (int i = 0; i < 5; ++i) {
    WT_h[i] = (ushort*)alloc(1024 * 1024 * 2);
    WT_l[i] = (ushort*)alloc(1024 * 1024 * 2);
  }
  ushort* w1T = (ushort*)alloc(256 * 1024 * 2);       // N-pad to 256 rows
  ushort* tdw1T = (ushort*)alloc(128 * 1024 * 2);     // N-pad to 128 rows
  ushort* tdw2T = (ushort*)alloc(1024 * 64 * 2);      // K-pad to 64 (zero-filled)
  ushort* w2T = (ushort*)alloc(5 * 1024 * 64 * 2);    // K-pad to 64 (zero-filled)
  ushort* xxh = (ushort*)alloc(4096ull * 1024 * 2);
  ushort* m1h = (ushort*)alloc(4096ull * 160 * 2 + 256);  // +pad: K-tile overread on last row
  ushort* Xh = (ushort*)alloc(4096ull * 1024 * 2);
  ushort* Xl = (ushort*)alloc(4096ull * 1024 * 2);
  ushort* tdhh = (ushort*)alloc(4096ull * 32 * 2 + 256);
  float* r_f = (float*)alloc(16777216);
  float* k_f = (float*)alloc(16777216);
  float* v_f = (float*)alloc(16777216);
  float* w_f = (float*)alloc(16777216);
  float* g_f = (float*)alloc(16777216);
  float* so_f = (float*)alloc(16777216);
  ushort* yh = (ushort*)alloc(8388608);
  ushort* yl = (ushort*)alloc(8388608);

  // weight conversion (transpose to B^T, bf16 hi/lo split for the big five)
  ConvBig cb;
  for (int i = 0; i < 5; ++i) { cb.s[i] = W[i]; cb.oh[i] = WT_h[i]; cb.ol[i] = WT_l[i]; }
  conv_big_k<<<dim3(32, 32, 5), 256, 0, stream>>>(cb);
  ConvSmall cs;
  cs.s[0] = w1;   cs.oh[0] = w1T;   cs.R[0] = 1024; cs.C[0] = 160;  cs.ldo[0] = 1024;
  cs.s[1] = tdw1; cs.oh[1] = tdw1T; cs.R[1] = 1024; cs.C[1] = 32;   cs.ldo[1] = 1024;
  cs.s[2] = tdw2; cs.oh[2] = tdw2T; cs.R[2] = 32;   cs.C[2] = 1024; cs.ldo[2] = 64;
  for (int i = 0; i < 5; ++i) {
    cs.s[3 + i] = w2 + (size_t)i * 32 * 1024;
    cs.oh[3 + i] = w2T + (size_t)i * 1024 * 64;
    cs.R[3 + i] = 32; cs.C[3 + i] = 1024; cs.ldo[3 + i] = 64;
  }
  conv_small_k<<<dim3(32, 32, 8), 256, 0, stream>>>(cs);

  mixx_k<<<dim3(4096), 256, 0, stream>>>(inp, shifted, maa_x, xxh);

  auto G = [&](const ushort* Ah, const ushort* Al, int lda, const ushort* Bh, const ushort* Bl, int ldb,
               int N, int K, void* out0, void* out1, int epi, int split,
               const float* a0, const float* a1, const float* a2) {
    GemmP p{Ah, Al, Bh, Bl, out0, out1, a0, a1, a2, lda, ldb, 4096, N, K, epi, split};
    gemm_k<<<dim3(32, (N + 127) / 128), 256, 0, stream>>>(p);
  };

  // m1 = tanh(xxx @ W1)   (4096 x 160)
  G(xxh, nullptr, 1024, w1T, nullptr, 1024, 160, 1024, m1h, nullptr, 1, 0, nullptr, nullptr, nullptr);
  // gate i (order w,k,v,r,g): Xi = x + (prev-x)*(maa_i + m1[:,32i:+32] @ w2[i]) -> bf16 hi/lo
  // w-gate first, then its decay GEMM
  G(m1h + 0, nullptr, 160, w2T + 0 * 65536, nullptr, 64, 1024, 32, Xh, Xl, 3, 0, inp, shifted, maa[0]);
  G(Xh, nullptr, 1024, tdw1T, nullptr, 1024, 32, 1024, tdhh, nullptr, 1, 0, nullptr, nullptr, nullptr);
  // r
  G(m1h + 96, nullptr, 160, w2T + 3 * 65536, nullptr, 64, 1024, 32, Xh, Xl, 3, 0, inp, shifted, maa[3]);
  G(Xh, Xl, 1024, WT_h[0], WT_l[0], 1024, 1024, 1024, r_f, nullptr, 0, 1, nullptr, nullptr, nullptr);
  // k
  G(m1h + 32, nullptr, 160, w2T + 1 * 65536, nullptr, 64, 1024, 32, Xh, Xl, 3, 0, inp, shifted, maa[1]);
  G(Xh, Xl, 1024, WT_h[1], WT_l[1], 1024, 1024, 1024, k_f, nullptr, 0, 1, nullptr, nullptr, nullptr);
  // v
  G(m1h + 64, nullptr, 160, w2T + 2 * 65536, nullptr, 64, 1024, 32, Xh, Xl, 3, 0, inp, shifted, maa[2]);
  G(Xh, Xl, 1024, WT_h[2], WT_l[2], 1024, 1024, 1024, v_f, nullptr, 0, 1, nullptr, nullptr, nullptr);
  // g (swish epilogue)
  G(m1h + 128, nullptr, 160, w2T + 4 * 65536, nullptr, 64, 1024, 32, Xh, Xl, 3, 0, inp, shifted, maa[4]);
  G(Xh, Xl, 1024, WT_h[3], WT_l[3], 1024, 1024, 1024, g_f, nullptr, 2, 1, nullptr, nullptr, nullptr);
  // w = exp(-exp(tdh @ tdw2 + time_decay))
  G(tdhh, nullptr, 32, tdw2T, nullptr, 64, 1024, 32, w_f, nullptr, 4, 0, tdec, nullptr, nullptr);

  float* stateOut = (float*)d_out + 4194304 + 4096;
  wkv_k<<<dim3(512), 256, 0, stream>>>(r_f, k_f, v_f, w_f, tf, st0, so_f, stateOut);
  gn_k<<<dim3(1024, 16), 256, 0, stream>>>(so_f, g_f, gsc, gbi, yh, yl);
  // final: (y*g) @ Wo -> d_out
  G(yh, yl, 1024, WT_h[4], WT_l[4], 1024, 1024, 1024, (float*)d_out, nullptr, 0, 1, nullptr, nullptr, nullptr);
  // new_shifted = inputs[-1]
  hipMemcpyAsync((float*)d_out + 4194304, inp + 4096ull * 1023, 4096 * sizeof(float),
                 hipMemcpyDeviceToDevice, stream);
}

// Round 7
// 883.167 us; speedup vs baseline: 1.1879x; 1.1879x over previous
//
#include <hip/hip_runtime.h>

using uint = unsigned int;
using ushort = unsigned short;
using f32x4 = __attribute__((ext_vector_type(4))) float;
using bf16x8 = __attribute__((ext_vector_type(8))) short;

// ---------- helpers ----------
__device__ __forceinline__ ushort f2bf(float x) {
  uint b = __float_as_uint(x);
  return (ushort)((b + 0x7FFFu + ((b >> 16) & 1u)) >> 16);
}
__device__ __forceinline__ float bf2f(ushort u) { return __uint_as_float(((uint)u) << 16); }

__device__ __forceinline__ void gload16(const void* g, void* l) {
  __builtin_amdgcn_global_load_lds((const __attribute__((address_space(1))) void*)g,
                                   (__attribute__((address_space(3))) void*)l, 16, 0, 0);
}
__device__ __forceinline__ void gload4(const void* g, void* l) {
  __builtin_amdgcn_global_load_lds((const __attribute__((address_space(1))) void*)g,
                                   (__attribute__((address_space(3))) void*)l, 4, 0, 0);
}

struct __align__(8) U4 { ushort x, y, z, w; };

// ---------- transpose + bf16 split convert: src (R,C) f32 -> out (C rows, ldo cols), zero for r>=R ----------
__device__ __forceinline__ void convT_impl(const float* src, ushort* oh, ushort* ol, int R, int C, int ldo) {
  const int r0 = blockIdx.x * 32, c0 = blockIdx.y * 32;
  if (r0 >= ldo || c0 >= C) return;
  __shared__ float tile[32][33];
  const int tx = threadIdx.x & 31, ty = threadIdx.x >> 5;
#pragma unroll
  for (int j = 0; j < 4; ++j) {
    const int r = r0 + ty + j * 8;
    tile[ty + j * 8][tx] = (r < R) ? src[(size_t)r * C + c0 + tx] : 0.f;
  }
  __syncthreads();
#pragma unroll
  for (int j = 0; j < 4; ++j) {
    const int c = c0 + ty + j * 8;
    const int r = r0 + tx;
    const float v = tile[tx][ty + j * 8];
    const ushort hb = f2bf(v);
    oh[(size_t)c * ldo + r] = hb;
    if (ol) ol[(size_t)c * ldo + r] = f2bf(v - bf2f(hb));
  }
}

struct ConvBig { const float* s[5]; ushort* oh[5]; ushort* ol[5]; };
__global__ void conv_big_k(ConvBig a) {
  const int z = blockIdx.z;
  convT_impl(a.s[z], a.oh[z], a.ol[z], 1024, 1024, 1024);
}

struct ConvSmall { const float* s[8]; ushort* oh[8]; int R[8]; int C[8]; int ldo[8]; };
__global__ void conv_small_k(ConvSmall a) {
  const int z = blockIdx.z;
  convT_impl(a.s[z], a.oh[z], nullptr, a.R[z], a.C[z], a.ldo[z]);
}

// ---------- token-shift mix for xxx = x + (prev - x)*time_maa_x  -> bf16 (hi only) ----------
__global__ void mixx_k(const float* __restrict__ x, const float* __restrict__ sh,
                       const float* __restrict__ maa, ushort* __restrict__ xh) {
  const size_t i = ((size_t)blockIdx.x * 256 + threadIdx.x) * 4;
  const size_t row = i >> 10;
  const int col = (int)(i & 1023);
  const float4 xv = *(const float4*)(x + i);
  const float4 pv = (row < 4) ? *(const float4*)(sh + i) : *(const float4*)(x + i - 4096);
  const float4 mv = *(const float4*)(maa + col);
  U4 o;
  o.x = f2bf(xv.x + (pv.x - xv.x) * mv.x);
  o.y = f2bf(xv.y + (pv.y - xv.y) * mv.y);
  o.z = f2bf(xv.z + (pv.z - xv.z) * mv.z);
  o.w = f2bf(xv.w + (pv.w - xv.w) * mv.w);
  *(U4*)(xh + i) = o;
}

// ---------- GEMM: C(M=4096, N) = A(M,K) @ B(K,N), A row-major bf16 h/l, B given as B^T (N,K) bf16 h/l ----------
struct GemmP {
  const ushort *Ah, *Al, *Bh, *Bl;
  void *out0, *out1;
  const float *aux0, *aux1, *aux2;
  int lda, ldb, M, N, K, epi, split;
};

__device__ __forceinline__ bf16x8 fragld(const ushort* smbase, int byteOff, int rb, int ks, int l) {
  const int row = rb + (l & 15);
  const int kb = (ks << 6) | (((l >> 4) & 3) << 4);
  const int off = byteOff + row * 128 + (kb ^ ((row & 7) << 4));
  return *(const bf16x8*)((const char*)smbase + off);
}

__global__ __launch_bounds__(256, 2) void gemm_k(GemmP p) {
  __shared__ __align__(16) ushort sm[32768];  // 64KB: Ah | Bh | Al | Bl, 16KB each
  const int t = threadIdx.x;
  const int l = t & 63, wid = t >> 6;
  const int wm = wid >> 1, wn = wid & 1;
  const int bm = blockIdx.x, bn = blockIdx.y;

  f32x4 acc[4][4];
#pragma unroll
  for (int i = 0; i < 4; ++i)
#pragma unroll
    for (int j = 0; j < 4; ++j) acc[i][j] = (f32x4){0.f, 0.f, 0.f, 0.f};

  const int srow = t >> 3;         // 0..31
  const int skb = (t & 7) << 4;    // 0..112
  const int KT = (p.K + 63) >> 6;

  for (int kt = 0; kt < KT; ++kt) {
    const int k0 = kt << 6;
    __syncthreads();
#pragma unroll
    for (int j = 0; j < 4; ++j) {
      const int row = srow + j * 32;
      const int srcK = k0 + ((skb ^ ((row & 7) << 4)) >> 1);
      gload16(p.Ah + (size_t)(bm * 128 + row) * p.lda + srcK, (char*)sm + row * 128 + skb);
      gload16(p.Bh + (size_t)(bn * 128 + row) * p.ldb + srcK, (char*)sm + 16384 + row * 128 + skb);
    }
    if (p.split) {
#pragma unroll
      for (int j = 0; j < 4; ++j) {
        const int row = srow + j * 32;
        const int srcK = k0 + ((skb ^ ((row & 7) << 4)) >> 1);
        gload16(p.Al + (size_t)(bm * 128 + row) * p.lda + srcK, (char*)sm + 32768 + row * 128 + skb);
        gload16(p.Bl + (size_t)(bn * 128 + row) * p.ldb + srcK, (char*)sm + 49152 + row * 128 + skb);
      }
    }
    __syncthreads();
#pragma unroll
    for (int ks = 0; ks < 2; ++ks) {
      bf16x8 ah[4], bh[4];
#pragma unroll
      for (int f = 0; f < 4; ++f) {
        ah[f] = fragld(sm, 0, wm * 64 + f * 16, ks, l);
        bh[f] = fragld(sm, 16384, wn * 64 + f * 16, ks, l);
      }
      if (p.split) {
        bf16x8 al[4], bl[4];
#pragma unroll
        for (int f = 0; f < 4; ++f) {
          al[f] = fragld(sm, 32768, wm * 64 + f * 16, ks, l);
          bl[f] = fragld(sm, 49152, wn * 64 + f * 16, ks, l);
        }
#pragma unroll
        for (int mf = 0; mf < 4; ++mf)
#pragma unroll
          for (int nf = 0; nf < 4; ++nf) {
            acc[mf][nf] = __builtin_amdgcn_mfma_f32_16x16x32_bf16(ah[mf], bh[nf], acc[mf][nf], 0, 0, 0);
            acc[mf][nf] = __builtin_amdgcn_mfma_f32_16x16x32_bf16(ah[mf], bl[nf], acc[mf][nf], 0, 0, 0);
            acc[mf][nf] = __builtin_amdgcn_mfma_f32_16x16x32_bf16(al[mf], bh[nf], acc[mf][nf], 0, 0, 0);
          }
      } else {
#pragma unroll
        for (int mf = 0; mf < 4; ++mf)
#pragma unroll
          for (int nf = 0; nf < 4; ++nf)
            acc[mf][nf] = __builtin_amdgcn_mfma_f32_16x16x32_bf16(ah[mf], bh[nf], acc[mf][nf], 0, 0, 0);
      }
    }
  }

  const int rb0 = bm * 128 + wm * 64 + ((l >> 4) << 2);
  const int cb0 = bn * 128 + wn * 64 + (l & 15);
#pragma unroll
  for (int mf = 0; mf < 4; ++mf) {
#pragma unroll
    for (int nf = 0; nf < 4; ++nf) {
      const int col = cb0 + nf * 16;
      if (col >= p.N) continue;
#pragma unroll
      for (int jj = 0; jj < 4; ++jj) {
        const int row = rb0 + mf * 16 + jj;
        const float v = acc[mf][nf][jj];
        const size_t o = (size_t)row * p.N + col;
        if (p.epi == 0) {
          ((float*)p.out0)[o] = v;
        } else if (p.epi == 1) {           // tanh -> bf16 (hi)
          ((ushort*)p.out0)[o] = f2bf(tanhf(v));
        } else if (p.epi == 2) {           // swish -> f32
          ((float*)p.out0)[o] = v / (1.f + expf(-v));
        } else if (p.epi == 3) {           // token-shift mix -> bf16 hi/lo
          const float x = p.aux0[(size_t)row * 1024 + col];
          const float pv = (row < 4) ? p.aux1[(size_t)row * 1024 + col]
                                     : p.aux0[(size_t)(row - 4) * 1024 + col];
          const float xi = x + (pv - x) * (p.aux2[col] + v);
          const ushort hb = f2bf(xi);
          ((ushort*)p.out0)[o] = hb;
          ((ushort*)p.out1)[o] = f2bf(xi - bf2f(hb));
        } else {                            // epi==4: w = exp(-exp(acc + time_decay[c])) -> f32
          ((float*)p.out0)[o] = expf(-expf(v + p.aux0[col]));
        }
      }
    }
  }
}

// ---------- WKV6 scan: chunked LDS double-buffer pipeline ----------
// block = (bh, mg): bh = blockIdx&63 so the 8 mg-siblings of a bh share an XCD (L2 reuse of r/k/w).
// Per chunk: stage 32 t-steps of r/k/w (64 floats each) + v (8 floats, this mg) into LDS via
// global_load_lds; one barrier per chunk; 32 compute iterations from LDS.
// Lane owns state rows (n, n+1) of column m; 5-step shuffle reduce over 32 lanes per output.
__global__ __launch_bounds__(256) void wkv_k(const float* __restrict__ rf, const float* __restrict__ kf,
                                             const float* __restrict__ vf, const float* __restrict__ wf,
                                             const float* __restrict__ tf, const float* __restrict__ st0,
                                             float* __restrict__ so, float* __restrict__ stO) {
  __shared__ __align__(16) float sr[2][32][64], sk[2][32][64], sw[2][32][64];
  __shared__ __align__(16) float sv[2][32][8];
  const int tl = threadIdx.x;
  const int l = tl & 63, wid = tl >> 6;
  const int bh = blockIdx.x & 63;   // same-bh siblings adjacent mod 8 -> same XCD
  const int mg = blockIdx.x >> 6;   // 0..7
  const int b = bh >> 4, h = bh & 15;
  const int ml = wid * 2 + (l >> 5);   // 0..7
  const int m = mg * 8 + ml;
  const int n = (l & 31) << 1;
  const size_t bOff = (size_t)b * 1024 + h * 64;

  const size_t sOff = ((size_t)bh * 64 + n) * 64 + m;
  float s0 = st0[sOff], s1 = st0[sOff + 64];
  const float u0 = tf[h * 64 + n], u1 = tf[h * 64 + n + 1];

  // staging thread roles
  const int tloc = tl >> 4;            // 0..15 (t within half-chunk)
  const int n4 = (tl & 15) << 2;       // 0..60
  const int tv = tl >> 3, mv = tl & 7; // v: 32 t x 8 m

  auto stage = [&](int bufS, int c) {
    const size_t g0 = (size_t)(c << 5) * 4096 + bOff;
    const size_t ga = g0 + (size_t)tloc * 4096 + n4;
    gload16(rf + ga, &sr[bufS][tloc][n4]);
    gload16(kf + ga, &sk[bufS][tloc][n4]);
    gload16(wf + ga, &sw[bufS][tloc][n4]);
    const size_t gb = ga + 16 * 4096;
    gload16(rf + gb, &sr[bufS][tloc + 16][n4]);
    gload16(kf + gb, &sk[bufS][tloc + 16][n4]);
    gload16(wf + gb, &sw[bufS][tloc + 16][n4]);
    gload4(vf + g0 + (size_t)tv * 4096 + (mg << 3) + mv, &sv[bufS][tv][mv]);
  };

  stage(0, 0);
  size_t obase = bOff;
  int buf = 0;
  for (int c = 0; c < 32; ++c) {
    __syncthreads();                 // drains vmcnt -> chunk c resident in buf
    if (c + 1 < 32) stage(buf ^ 1, c + 1);  // loads fly during the 32-iter compute below
#pragma unroll 4
    for (int tt = 0; tt < 32; ++tt) {
      const float2 r2 = *(const float2*)&sr[buf][tt][n];
      const float2 k2 = *(const float2*)&sk[buf][tt][n];
      const float2 w2 = *(const float2*)&sw[buf][tt][n];
      const float vm = sv[buf][tt][ml];
      const float kv0 = k2.x * vm, kv1 = k2.y * vm;
      float pr = r2.x * fmaf(u0, kv0, s0) + r2.y * fmaf(u1, kv1, s1);
      s0 = fmaf(w2.x, s0, kv0);
      s1 = fmaf(w2.y, s1, kv1);
      pr += __shfl_xor(pr, 1);
      pr += __shfl_xor(pr, 2);
      pr += __shfl_xor(pr, 4);
      pr += __shfl_xor(pr, 8);
      pr += __shfl_xor(pr, 16);
      if ((l & 31) == 0) so[obase + m] = pr;
      obase += 4096;
    }
    buf ^= 1;
  }
  stO[sOff] = s0;
  stO[sOff + 64] = s1;
}

// ---------- GroupNorm over (B, N) per (t,h), fused *g gate, -> bf16 hi/lo ----------
__global__ __launch_bounds__(256) void gn_k(const float* __restrict__ so, const float* __restrict__ gf,
                                            const float* __restrict__ sc, const float* __restrict__ bi,
                                            ushort* __restrict__ yh, ushort* __restrict__ yl) {
  const int tdx = threadIdx.x;
  const int b = tdx >> 6, n = tdx & 63;
  const int t = blockIdx.x, h = blockIdx.y;
  const size_t idx = (size_t)t * 4096 + (size_t)b * 1024 + h * 64 + n;
  const float v = so[idx];
  float s = v, s2 = v * v;
#pragma unroll
  for (int off = 1; off < 64; off <<= 1) {
    s += __shfl_xor(s, off);
    s2 += __shfl_xor(s2, off);
  }
  __shared__ float ps[4], ps2[4];
  if ((tdx & 63) == 0) { ps[b] = s; ps2[b] = s2; }
  __syncthreads();
  const float S = ps[0] + ps[1] + ps[2] + ps[3];
  const float S2 = ps2[0] + ps2[1] + ps2[2] + ps2[3];
  const float mean = S * (1.f / 256.f);
  const float var = S2 * (1.f / 256.f) - mean * mean;
  const float inv = rsqrtf(var + 6.4e-4f);  // eps = 1e-5 * 8^2
  const int c = h * 64 + n;
  float y = (v - mean) * inv * sc[c] + bi[c];
  y *= gf[idx];
  const ushort hb = f2bf(y);
  yh[idx] = hb;
  yl[idx] = f2bf(y - bf2f(hb));
}

// ---------- host ----------
extern "C" void kernel_launch(void* const* d_in, const int* in_sizes, int n_in,
                              void* d_out, int out_size, void* d_ws, size_t ws_size,
                              hipStream_t stream) {
  const float* inp = (const float*)d_in[0];
  const float* shifted = (const float*)d_in[1];
  const float* st0 = (const float*)d_in[2];
  const float* maa_x = (const float*)d_in[3];
  const float* maa[5] = {(const float*)d_in[4], (const float*)d_in[5], (const float*)d_in[6],
                         (const float*)d_in[7], (const float*)d_in[8]};  // w,k,v,r,g
  const float* w1 = (const float*)d_in[9];
  const float* w2 = (const float*)d_in[10];
  const float* W[5] = {(const float*)d_in[11], (const float*)d_in[12], (const float*)d_in[13],
                       (const float*)d_in[14], (const float*)d_in[15]};  // Wr Wk Wv Wg Wo
  const float* tdw1 = (const float*)d_in[16];
  const float* tdw2 = (const float*)d_in[17];
  const float* tdec = (const float*)d_in[18];
  const float* tf = (const float*)d_in[19];
  const float* gsc = (const float*)d_in[20];
  const float* gbi = (const float*)d_in[21];
  (void)in_sizes; (void)n_in; (void)out_size; (void)ws_size;

  char* ws = (char*)d_ws;
  size_t cur = 0;
  auto alloc = [&](size_t bytes) { char* r = ws + cur; cur += (bytes + 255) & ~(size_t)255; return r; };
  ushort *WT_h[5], *WT_l[5];
  for (int i = 0; i < 5; ++i) {
    WT_h[i] = (ushort*)alloc(1024 * 1024 * 2);
    WT_l[i] = (ushort*)alloc(1024 * 1024 * 2);
  }
  ushort* w1T = (ushort*)alloc(256 * 1024 * 2);       // N-pad to 256 rows
  ushort* tdw1T = (ushort*)alloc(128 * 1024 * 2);     // N-pad to 128 rows
  ushort* tdw2T = (ushort*)alloc(1024 * 64 * 2);      // K-pad to 64 (zero-filled)
  ushort* w2T = (ushort*)alloc(5 * 1024 * 64 * 2);    // K-pad to 64 (zero-filled)
  ushort* xxh = (ushort*)alloc(4096ull * 1024 * 2);
  ushort* m1h = (ushort*)alloc(4096ull * 160 * 2 + 256);  // +pad: K-tile overread on last row
  ushort* Xh = (ushort*)alloc(4096ull * 1024 * 2);
  ushort* Xl = (ushort*)alloc(4096ull * 1024 * 2);
  ushort* tdhh = (ushort*)alloc(4096ull * 32 * 2 + 256);
  float* r_f = (float*)alloc(16777216);
  float* k_f = (float*)alloc(16777216);
  float* v_f = (float*)alloc(16777216);
  float* w_f = (float*)alloc(16777216);
  float* g_f = (float*)alloc(16777216);
  float* so_f = (float*)alloc(16777216);
  ushort* yh = (ushort*)alloc(8388608);
  ushort* yl = (ushort*)alloc(8388608);

  ConvBig cb;
  for (int i = 0; i < 5; ++i) { cb.s[i] = W[i]; cb.oh[i] = WT_h[i]; cb.ol[i] = WT_l[i]; }
  conv_big_k<<<dim3(32, 32, 5), 256, 0, stream>>>(cb);
  ConvSmall cs;
  cs.s[0] = w1;   cs.oh[0] = w1T;   cs.R[0] = 1024; cs.C[0] = 160;  cs.ldo[0] = 1024;
  cs.s[1] = tdw1; cs.oh[1] = tdw1T; cs.R[1] = 1024; cs.C[1] = 32;   cs.ldo[1] = 1024;
  cs.s[2] = tdw2; cs.oh[2] = tdw2T; cs.R[2] = 32;   cs.C[2] = 1024; cs.ldo[2] = 64;
  for (int i = 0; i < 5; ++i) {
    cs.s[3 + i] = w2 + (size_t)i * 32 * 1024;
    cs.oh[3 + i] = w2T + (size_t)i * 1024 * 64;
    cs.R[3 + i] = 32; cs.C[3 + i] = 1024; cs.ldo[3 + i] = 64;
  }
  conv_small_k<<<dim3(32, 32, 8), 256, 0, stream>>>(cs);

  mixx_k<<<dim3(4096), 256, 0, stream>>>(inp, shifted, maa_x, xxh);

  auto G = [&](const ushort* Ah, const ushort* Al, int lda, const ushort* Bh, const ushort* Bl, int ldb,
               int N, int K, void* out0, void* out1, int epi, int split,
               const float* a0, const float* a1, const float* a2) {
    GemmP p{Ah, Al, Bh, Bl, out0, out1, a0, a1, a2, lda, ldb, 4096, N, K, epi, split};
    gemm_k<<<dim3(32, (N + 127) / 128), 256, 0, stream>>>(p);
  };

  // m1 = tanh(xxx @ W1)   (4096 x 160)
  G(xxh, nullptr, 1024, w1T, nullptr, 1024, 160, 1024, m1h, nullptr, 1, 0, nullptr, nullptr, nullptr);
  // gate i (order w,k,v,r,g): Xi = x + (prev-x)*(maa_i + m1[:,32i:+32] @ w2[i]) -> bf16 hi/lo
  G(m1h + 0, nullptr, 160, w2T + 0 * 65536, nullptr, 64, 1024, 32, Xh, Xl, 3, 0, inp, shifted, maa[0]);
  G(Xh, nullptr, 1024, tdw1T, nullptr, 1024, 32, 1024, tdhh, nullptr, 1, 0, nullptr, nullptr, nullptr);
  // r
  G(m1h + 96, nullptr, 160, w2T + 3 * 65536, nullptr, 64, 1024, 32, Xh, Xl, 3, 0, inp, shifted, maa[3]);
  G(Xh, Xl, 1024, WT_h[0], WT_l[0], 1024, 1024, 1024, r_f, nullptr, 0, 1, nullptr, nullptr, nullptr);
  // k
  G(m1h + 32, nullptr, 160, w2T + 1 * 65536, nullptr, 64, 1024, 32, Xh, Xl, 3, 0, inp, shifted, maa[1]);
  G(Xh, Xl, 1024, WT_h[1], WT_l[1], 1024, 1024, 1024, k_f, nullptr, 0, 1, nullptr, nullptr, nullptr);
  // v
  G(m1h + 64, nullptr, 160, w2T + 2 * 65536, nullptr, 64, 1024, 32, Xh, Xl, 3, 0, inp, shifted, maa[2]);
  G(Xh, Xl, 1024, WT_h[2], WT_l[2], 1024, 1024, 1024, v_f, nullptr, 0, 1, nullptr, nullptr, nullptr);
  // g (swish epilogue)
  G(m1h + 128, nullptr, 160, w2T + 4 * 65536, nullptr, 64, 1024, 32, Xh, Xl, 3, 0, inp, shifted, maa[4]);
  G(Xh, Xl, 1024, WT_h[3], WT_l[3], 1024, 1024, 1024, g_f, nullptr, 2, 1, nullptr, nullptr, nullptr);
  // w = exp(-exp(tdh @ tdw2 + time_decay))
  G(tdhh, nullptr, 32, tdw2T, nullptr, 64, 1024, 32, w_f, nullptr, 4, 0, tdec, nullptr, nullptr);

  float* stateOut = (float*)d_out + 4194304 + 4096;
  wkv_k<<<dim3(512), 256, 0, stream>>>(r_f, k_f, v_f, w_f, tf, st0, so_f, stateOut);
  gn_k<<<dim3(1024, 16), 256, 0, stream>>>(so_f, g_f, gsc, gbi, yh, yl);
  // final: (y*g) @ Wo -> d_out
  G(yh, yl, 1024, WT_h[4], WT_l[4], 1024, 1024, 1024, (float*)d_out, nullptr, 0, 1, nullptr, nullptr, nullptr);
  // new_shifted = inputs[-1]
  hipMemcpyAsync((float*)d_out + 4194304, inp + 4096ull * 1023, 4096 * sizeof(float),
                 hipMemcpyDeviceToDevice, stream);
}

// Round 9
// 869.196 us; speedup vs baseline: 1.2070x; 1.0161x over previous
//
#include <hip/hip_runtime.h>

using uint = unsigned int;
using ushort = unsigned short;
using f32x4 = __attribute__((ext_vector_type(4))) float;
using bf16x8 = __attribute__((ext_vector_type(8))) short;

// ---------- helpers ----------
__device__ __forceinline__ ushort f2bf(float x) {
  uint b = __float_as_uint(x);
  return (ushort)((b + 0x7FFFu + ((b >> 16) & 1u)) >> 16);
}
__device__ __forceinline__ float bf2f(ushort u) { return __uint_as_float(((uint)u) << 16); }

__device__ __forceinline__ void gload16(const void* g, void* l) {
  __builtin_amdgcn_global_load_lds((const __attribute__((address_space(1))) void*)g,
                                   (__attribute__((address_space(3))) void*)l, 16, 0, 0);
}

struct __align__(8) U4 { ushort x, y, z, w; };

// ---------- transpose + bf16 split convert: src (R,C) f32 -> out (C rows, ldo cols), zero for r>=R ----------
__device__ __forceinline__ void convT_impl(const float* src, ushort* oh, ushort* ol, int R, int C, int ldo) {
  const int r0 = blockIdx.x * 32, c0 = blockIdx.y * 32;
  if (r0 >= ldo || c0 >= C) return;
  __shared__ float tile[32][33];
  const int tx = threadIdx.x & 31, ty = threadIdx.x >> 5;
#pragma unroll
  for (int j = 0; j < 4; ++j) {
    const int r = r0 + ty + j * 8;
    tile[ty + j * 8][tx] = (r < R) ? src[(size_t)r * C + c0 + tx] : 0.f;
  }
  __syncthreads();
#pragma unroll
  for (int j = 0; j < 4; ++j) {
    const int c = c0 + ty + j * 8;
    const int r = r0 + tx;
    const float v = tile[tx][ty + j * 8];
    const ushort hb = f2bf(v);
    oh[(size_t)c * ldo + r] = hb;
    if (ol) ol[(size_t)c * ldo + r] = f2bf(v - bf2f(hb));
  }
}

struct ConvBig { const float* s[5]; ushort* oh[5]; ushort* ol[5]; };
__global__ void conv_big_k(ConvBig a) {
  const int z = blockIdx.z;
  convT_impl(a.s[z], a.oh[z], a.ol[z], 1024, 1024, 1024);
}

struct ConvSmall { const float* s[8]; ushort* oh[8]; int R[8]; int C[8]; int ldo[8]; };
__global__ void conv_small_k(ConvSmall a) {
  const int z = blockIdx.z;
  convT_impl(a.s[z], a.oh[z], nullptr, a.R[z], a.C[z], a.ldo[z]);
}

// ---------- token-shift mix for xxx = x + (prev - x)*time_maa_x  -> bf16 (hi only) ----------
__global__ void mixx_k(const float* __restrict__ x, const float* __restrict__ sh,
                       const float* __restrict__ maa, ushort* __restrict__ xh) {
  const size_t i = ((size_t)blockIdx.x * 256 + threadIdx.x) * 4;
  const size_t row = i >> 10;
  const int col = (int)(i & 1023);
  const float4 xv = *(const float4*)(x + i);
  const float4 pv = (row < 4) ? *(const float4*)(sh + i) : *(const float4*)(x + i - 4096);
  const float4 mv = *(const float4*)(maa + col);
  U4 o;
  o.x = f2bf(xv.x + (pv.x - xv.x) * mv.x);
  o.y = f2bf(xv.y + (pv.y - xv.y) * mv.y);
  o.z = f2bf(xv.z + (pv.z - xv.z) * mv.z);
  o.w = f2bf(xv.w + (pv.w - xv.w) * mv.w);
  *(U4*)(xh + i) = o;
}

// ---------- GEMM: C(M=4096, N) = A(M,K) @ B(K,N), A row-major bf16 h/l, B given as B^T (N,K) bf16 h/l ----------
struct GemmP {
  const ushort *Ah, *Al, *Bh, *Bl;
  void *out0, *out1;
  const float *aux0, *aux1, *aux2;
  int lda, ldb, M, N, K, epi, split;
};

__device__ __forceinline__ bf16x8 fragld(const ushort* smbase, int byteOff, int rb, int ks, int l) {
  const int row = rb + (l & 15);
  const int kb = (ks << 6) | (((l >> 4) & 3) << 4);
  const int off = byteOff + row * 128 + (kb ^ ((row & 7) << 4));
  return *(const bf16x8*)((const char*)smbase + off);
}

__global__ __launch_bounds__(256, 2) void gemm_k(GemmP p) {
  __shared__ __align__(16) ushort sm[32768];  // 64KB: Ah | Bh | Al | Bl, 16KB each
  const int t = threadIdx.x;
  const int l = t & 63, wid = t >> 6;
  const int wm = wid >> 1, wn = wid & 1;
  const int bm = blockIdx.x, bn = blockIdx.y;

  f32x4 acc[4][4];
#pragma unroll
  for (int i = 0; i < 4; ++i)
#pragma unroll
    for (int j = 0; j < 4; ++j) acc[i][j] = (f32x4){0.f, 0.f, 0.f, 0.f};

  const int srow = t >> 3;         // 0..31
  const int skb = (t & 7) << 4;    // 0..112
  const int KT = (p.K + 63) >> 6;

  for (int kt = 0; kt < KT; ++kt) {
    const int k0 = kt << 6;
    __syncthreads();
#pragma unroll
    for (int j = 0; j < 4; ++j) {
      const int row = srow + j * 32;
      const int srcK = k0 + ((skb ^ ((row & 7) << 4)) >> 1);
      gload16(p.Ah + (size_t)(bm * 128 + row) * p.lda + srcK, (char*)sm + row * 128 + skb);
      gload16(p.Bh + (size_t)(bn * 128 + row) * p.ldb + srcK, (char*)sm + 16384 + row * 128 + skb);
    }
    if (p.split) {
#pragma unroll
      for (int j = 0; j < 4; ++j) {
        const int row = srow + j * 32;
        const int srcK = k0 + ((skb ^ ((row & 7) << 4)) >> 1);
        gload16(p.Al + (size_t)(bm * 128 + row) * p.lda + srcK, (char*)sm + 32768 + row * 128 + skb);
        gload16(p.Bl + (size_t)(bn * 128 + row) * p.ldb + srcK, (char*)sm + 49152 + row * 128 + skb);
      }
    }
    __syncthreads();
#pragma unroll
    for (int ks = 0; ks < 2; ++ks) {
      bf16x8 ah[4], bh[4];
#pragma unroll
      for (int f = 0; f < 4; ++f) {
        ah[f] = fragld(sm, 0, wm * 64 + f * 16, ks, l);
        bh[f] = fragld(sm, 16384, wn * 64 + f * 16, ks, l);
      }
      if (p.split) {
        bf16x8 al[4], bl[4];
#pragma unroll
        for (int f = 0; f < 4; ++f) {
          al[f] = fragld(sm, 32768, wm * 64 + f * 16, ks, l);
          bl[f] = fragld(sm, 49152, wn * 64 + f * 16, ks, l);
        }
#pragma unroll
        for (int mf = 0; mf < 4; ++mf)
#pragma unroll
          for (int nf = 0; nf < 4; ++nf) {
            acc[mf][nf] = __builtin_amdgcn_mfma_f32_16x16x32_bf16(ah[mf], bh[nf], acc[mf][nf], 0, 0, 0);
            acc[mf][nf] = __builtin_amdgcn_mfma_f32_16x16x32_bf16(ah[mf], bl[nf], acc[mf][nf], 0, 0, 0);
            acc[mf][nf] = __builtin_amdgcn_mfma_f32_16x16x32_bf16(al[mf], bh[nf], acc[mf][nf], 0, 0, 0);
          }
      } else {
#pragma unroll
        for (int mf = 0; mf < 4; ++mf)
#pragma unroll
          for (int nf = 0; nf < 4; ++nf)
            acc[mf][nf] = __builtin_amdgcn_mfma_f32_16x16x32_bf16(ah[mf], bh[nf], acc[mf][nf], 0, 0, 0);
      }
    }
  }

  const int rb0 = bm * 128 + wm * 64 + ((l >> 4) << 2);
  const int cb0 = bn * 128 + wn * 64 + (l & 15);
#pragma unroll
  for (int mf = 0; mf < 4; ++mf) {
#pragma unroll
    for (int nf = 0; nf < 4; ++nf) {
      const int col = cb0 + nf * 16;
      if (col >= p.N) continue;
#pragma unroll
      for (int jj = 0; jj < 4; ++jj) {
        const int row = rb0 + mf * 16 + jj;
        const float v = acc[mf][nf][jj];
        const size_t o = (size_t)row * p.N + col;
        if (p.epi == 0) {
          ((float*)p.out0)[o] = v;
        } else if (p.epi == 1) {           // tanh -> bf16 (hi)
          ((ushort*)p.out0)[o] = f2bf(tanhf(v));
        } else if (p.epi == 2) {           // swish -> f32
          ((float*)p.out0)[o] = v / (1.f + expf(-v));
        } else if (p.epi == 3) {           // token-shift mix -> bf16 hi/lo
          const float x = p.aux0[(size_t)row * 1024 + col];
          const float pv = (row < 4) ? p.aux1[(size_t)row * 1024 + col]
                                     : p.aux0[(size_t)(row - 4) * 1024 + col];
          const float xi = x + (pv - x) * (p.aux2[col] + v);
          const ushort hb = f2bf(xi);
          ((ushort*)p.out0)[o] = hb;
          ((ushort*)p.out1)[o] = f2bf(xi - bf2f(hb));
        } else {                            // epi==4: w = exp(-exp(acc + time_decay[c])) -> f32
          ((float*)p.out0)[o] = expf(-expf(v + p.aux0[col]));
        }
      }
    }
  }
}

// ---------- WKV6 scan v3: register-state, lane-local n-reduction ----------
// 64 lanes = 8 m-columns x 8 n-slices; each lane holds 8 state elements s[n0..n0+8)[m] in VGPRs.
// Per t-step: 6 ds_read_b128 (r/k/w slice) + 1 v read + 3 shfl_xor (vs 9 DS + 5 shfl before)
// -> per-CU DS-pipe load drops ~3.5x (the measured R7 bottleneck: 651 cyc/t-step DS-issue-bound).
// Block = 128 thr (2 waves) = 16 m's of one bh; grid 256 = 64 bh x 4 mg; bh = blockIdx&63 keeps
// the 4 mg-siblings on one XCD (r/k/w L2-shared). Chunked LDS double-buffer as before (T_CH=32).
#define TCH 32
__global__ __launch_bounds__(128) void wkv_k(const float* __restrict__ rf, const float* __restrict__ kf,
                                             const float* __restrict__ vf, const float* __restrict__ wf,
                                             const float* __restrict__ tf, const float* __restrict__ st0,
                                             float* __restrict__ so, float* __restrict__ stO) {
  __shared__ __align__(16) float sr[2][TCH][64], sk[2][TCH][64], sw[2][TCH][64], sv[2][TCH][16];
  const int tl = threadIdx.x;          // 0..127
  const int l = tl & 63, wid = tl >> 6;
  const int bh = blockIdx.x & 63;      // mg-siblings adjacent mod 64 -> same XCD
  const int mg = blockIdx.x >> 6;      // 0..3 (16 m's each)
  const int b = bh >> 4, h = bh & 15;
  const int slice = l & 7;             // n-slice: n in [slice*8, slice*8+8)
  const int ml = (wid << 3) + (l >> 3);  // m within block 0..15
  const int m = (mg << 4) + ml;        // global m 0..63
  const int n0 = slice << 3;
  const size_t bOff = (size_t)b * 1024 + h * 64;

  // state s[j] = state[bh][n0+j][m], u[j] = tf[h][n0+j]
  float s[8], u[8];
  const size_t sBase = ((size_t)bh * 64 + n0) * 64 + m;
#pragma unroll
  for (int j = 0; j < 8; ++j) s[j] = st0[sBase + (size_t)j * 64];
#pragma unroll
  for (int j = 0; j < 8; ++j) u[j] = tf[h * 64 + n0 + j];

  // staging roles: r/k/w in 4 rounds of 8 t-rows; LDS dst byte = tl*16 per round (linear -> valid
  // global_load_lds dest); v: 1 round, dst byte = tl*16.
  const int tq = tl >> 4;              // 0..7
  const int c16 = (tl & 15) << 2;      // float offset 0..60
  const int tv = tl >> 2, jv = (tl & 3) << 2;

  auto stage = [&](int bufS, int c) {
    const size_t g0 = (size_t)(c * TCH) * 4096 + bOff;
#pragma unroll
    for (int q = 0; q < 4; ++q) {
      const int trow = q * 8 + tq;
      const size_t ga = g0 + (size_t)trow * 4096 + c16;
      gload16(rf + ga, &sr[bufS][trow][c16]);
      gload16(kf + ga, &sk[bufS][trow][c16]);
      gload16(wf + ga, &sw[bufS][trow][c16]);
    }
    gload16(vf + g0 + (size_t)tv * 4096 + (mg << 4) + jv, &sv[bufS][tv][jv]);
  };

  stage(0, 0);
  int buf = 0;
  for (int c = 0; c < 1024 / TCH; ++c) {
    __syncthreads();                    // drains vmcnt -> chunk c resident in buf
    if (c + 1 < 1024 / TCH) stage(buf ^ 1, c + 1);
#pragma unroll 4
    for (int t = 0; t < TCH; ++t) {
      const float4 ra = *(const float4*)&sr[buf][t][n0];
      const float4 rb = *(const float4*)&sr[buf][t][n0 + 4];
      const float4 ka = *(const float4*)&sk[buf][t][n0];
      const float4 kb = *(const float4*)&sk[buf][t][n0 + 4];
      const float4 wa = *(const float4*)&sw[buf][t][n0];
      const float4 wb = *(const float4*)&sw[buf][t][n0 + 4];
      const float vm = sv[buf][t][ml];
      const float kv0 = ka.x * vm, kv1 = ka.y * vm, kv2 = ka.z * vm, kv3 = ka.w * vm;
      const float kv4 = kb.x * vm, kv5 = kb.y * vm, kv6 = kb.z * vm, kv7 = kb.w * vm;
      // out partial: sum_n r[n] * (u[n]*kv[n] + s_pre[n])
      float pA = ra.x * fmaf(u[0], kv0, s[0]);
      pA = fmaf(ra.y, fmaf(u[1], kv1, s[1]), pA);
      float pB = ra.z * fmaf(u[2], kv2, s[2]);
      pB = fmaf(ra.w, fmaf(u[3], kv3, s[3]), pB);
      float pC = rb.x * fmaf(u[4], kv4, s[4]);
      pC = fmaf(rb.y, fmaf(u[5], kv5, s[5]), pC);
      float pD = rb.z * fmaf(u[6], kv6, s[6]);
      pD = fmaf(rb.w, fmaf(u[7], kv7, s[7]), pD);
      // state update s' = w*s + kv
      s[0] = fmaf(wa.x, s[0], kv0);
      s[1] = fmaf(wa.y, s[1], kv1);
      s[2] = fmaf(wa.z, s[2], kv2);
      s[3] = fmaf(wa.w, s[3], kv3);
      s[4] = fmaf(wb.x, s[4], kv4);
      s[5] = fmaf(wb.y, s[5], kv5);
      s[6] = fmaf(wb.z, s[6], kv6);
      s[7] = fmaf(wb.w, s[7], kv7);
      float pr = (pA + pB) + (pC + pD);
      // reduce over the 8 slices (lanes l^1, l^2, l^4 share the same m)
      pr += __shfl_xor(pr, 1);
      pr += __shfl_xor(pr, 2);
      pr += __shfl_xor(pr, 4);
      if (slice == 0) so[(size_t)(c * TCH + t) * 4096 + bOff + m] = pr;
    }
    buf ^= 1;
  }
#pragma unroll
  for (int j = 0; j < 8; ++j) stO[sBase + (size_t)j * 64] = s[j];
}

// ---------- GroupNorm over (B, N) per (t,h), fused *g gate, -> bf16 hi/lo ----------
__global__ __launch_bounds__(256) void gn_k(const float* __restrict__ so, const float* __restrict__ gf,
                                            const float* __restrict__ sc, const float* __restrict__ bi,
                                            ushort* __restrict__ yh, ushort* __restrict__ yl) {
  const int tdx = threadIdx.x;
  const int b = tdx >> 6, n = tdx & 63;
  const int t = blockIdx.x, h = blockIdx.y;
  const size_t idx = (size_t)t * 4096 + (size_t)b * 1024 + h * 64 + n;
  const float v = so[idx];
  float s = v, s2 = v * v;
#pragma unroll
  for (int off = 1; off < 64; off <<= 1) {
    s += __shfl_xor(s, off);
    s2 += __shfl_xor(s2, off);
  }
  __shared__ float ps[4], ps2[4];
  if ((tdx & 63) == 0) { ps[b] = s; ps2[b] = s2; }
  __syncthreads();
  const float S = ps[0] + ps[1] + ps[2] + ps[3];
  const float S2 = ps2[0] + ps2[1] + ps2[2] + ps2[3];
  const float mean = S * (1.f / 256.f);
  const float var = S2 * (1.f / 256.f) - mean * mean;
  const float inv = rsqrtf(var + 6.4e-4f);  // eps = 1e-5 * 8^2
  const int c = h * 64 + n;
  float y = (v - mean) * inv * sc[c] + bi[c];
  y *= gf[idx];
  const ushort hb = f2bf(y);
  yh[idx] = hb;
  yl[idx] = f2bf(y - bf2f(hb));
}

// ---------- host ----------
extern "C" void kernel_launch(void* const* d_in, const int* in_sizes, int n_in,
                              void* d_out, int out_size, void* d_ws, size_t ws_size,
                              hipStream_t stream) {
  const float* inp = (const float*)d_in[0];
  const float* shifted = (const float*)d_in[1];
  const float* st0 = (const float*)d_in[2];
  const float* maa_x = (const float*)d_in[3];
  const float* maa[5] = {(const float*)d_in[4], (const float*)d_in[5], (const float*)d_in[6],
                         (const float*)d_in[7], (const float*)d_in[8]};  // w,k,v,r,g
  const float* w1 = (const float*)d_in[9];
  const float* w2 = (const float*)d_in[10];
  const float* W[5] = {(const float*)d_in[11], (const float*)d_in[12], (const float*)d_in[13],
                       (const float*)d_in[14], (const float*)d_in[15]};  // Wr Wk Wv Wg Wo
  const float* tdw1 = (const float*)d_in[16];
  const float* tdw2 = (const float*)d_in[17];
  const float* tdec = (const float*)d_in[18];
  const float* tf = (const float*)d_in[19];
  const float* gsc = (const float*)d_in[20];
  const float* gbi = (const float*)d_in[21];
  (void)in_sizes; (void)n_in; (void)out_size; (void)ws_size;

  char* ws = (char*)d_ws;
  size_t cur = 0;
  auto alloc = [&](size_t bytes) { char* r = ws + cur; cur += (bytes + 255) & ~(size_t)255; return r; };
  ushort *WT_h[5], *WT_l[5];
  for (int i = 0; i < 5; ++i) {
    WT_h[i] = (ushort*)alloc(1024 * 1024 * 2);
    WT_l[i] = (ushort*)alloc(1024 * 1024 * 2);
  }
  ushort* w1T = (ushort*)alloc(256 * 1024 * 2);       // N-pad to 256 rows
  ushort* tdw1T = (ushort*)alloc(128 * 1024 * 2);     // N-pad to 128 rows
  ushort* tdw2T = (ushort*)alloc(1024 * 64 * 2);      // K-pad to 64 (zero-filled)
  ushort* w2T = (ushort*)alloc(5 * 1024 * 64 * 2);    // K-pad to 64 (zero-filled)
  ushort* xxh = (ushort*)alloc(4096ull * 1024 * 2);
  ushort* m1h = (ushort*)alloc(4096ull * 160 * 2 + 256);  // +pad: K-tile overread on last row
  ushort* Xh = (ushort*)alloc(4096ull * 1024 * 2);
  ushort* Xl = (ushort*)alloc(4096ull * 1024 * 2);
  ushort* tdhh = (ushort*)alloc(4096ull * 32 * 2 + 256);
  float* r_f = (float*)alloc(16777216);
  float* k_f = (float*)alloc(16777216);
  float* v_f = (float*)alloc(16777216);
  float* w_f = (float*)alloc(16777216);
  float* g_f = (float*)alloc(16777216);
  float* so_f = (float*)alloc(16777216);
  ushort* yh = (ushort*)alloc(8388608);
  ushort* yl = (ushort*)alloc(8388608);

  ConvBig cb;
  for (int i = 0; i < 5; ++i) { cb.s[i] = W[i]; cb.oh[i] = WT_h[i]; cb.ol[i] = WT_l[i]; }
  conv_big_k<<<dim3(32, 32, 5), 256, 0, stream>>>(cb);
  ConvSmall cs;
  cs.s[0] = w1;   cs.oh[0] = w1T;   cs.R[0] = 1024; cs.C[0] = 160;  cs.ldo[0] = 1024;
  cs.s[1] = tdw1; cs.oh[1] = tdw1T; cs.R[1] = 1024; cs.C[1] = 32;   cs.ldo[1] = 1024;
  cs.s[2] = tdw2; cs.oh[2] = tdw2T; cs.R[2] = 32;   cs.C[2] = 1024; cs.ldo[2] = 64;
  for (int i = 0; i < 5; ++i) {
    cs.s[3 + i] = w2 + (size_t)i * 32 * 1024;
    cs.oh[3 + i] = w2T + (size_t)i * 1024 * 64;
    cs.R[3 + i] = 32; cs.C[3 + i] = 1024; cs.ldo[3 + i] = 64;
  }
  conv_small_k<<<dim3(32, 32, 8), 256, 0, stream>>>(cs);

  mixx_k<<<dim3(4096), 256, 0, stream>>>(inp, shifted, maa_x, xxh);

  auto G = [&](const ushort* Ah, const ushort* Al, int lda, const ushort* Bh, const ushort* Bl, int ldb,
               int N, int K, void* out0, void* out1, int epi, int split,
               const float* a0, const float* a1, const float* a2) {
    GemmP p{Ah, Al, Bh, Bl, out0, out1, a0, a1, a2, lda, ldb, 4096, N, K, epi, split};
    gemm_k<<<dim3(32, (N + 127) / 128), 256, 0, stream>>>(p);
  };

  // m1 = tanh(xxx @ W1)   (4096 x 160)
  G(xxh, nullptr, 1024, w1T, nullptr, 1024, 160, 1024, m1h, nullptr, 1, 0, nullptr, nullptr, nullptr);
  // gate i (order w,k,v,r,g): Xi = x + (prev-x)*(maa_i + m1[:,32i:+32] @ w2[i]) -> bf16 hi/lo
  G(m1h + 0, nullptr, 160, w2T + 0 * 65536, nullptr, 64, 1024, 32, Xh, Xl, 3, 0, inp, shifted, maa[0]);
  G(Xh, nullptr, 1024, tdw1T, nullptr, 1024, 32, 1024, tdhh, nullptr, 1, 0, nullptr, nullptr, nullptr);
  // r
  G(m1h + 96, nullptr, 160, w2T + 3 * 65536, nullptr, 64, 1024, 32, Xh, Xl, 3, 0, inp, shifted, maa[3]);
  G(Xh, Xl, 1024, WT_h[0], WT_l[0], 1024, 1024, 1024, r_f, nullptr, 0, 1, nullptr, nullptr, nullptr);
  // k
  G(m1h + 32, nullptr, 160, w2T + 1 * 65536, nullptr, 64, 1024, 32, Xh, Xl, 3, 0, inp, shifted, maa[1]);
  G(Xh, Xl, 1024, WT_h[1], WT_l[1], 1024, 1024, 1024, k_f, nullptr, 0, 1, nullptr, nullptr, nullptr);
  // v
  G(m1h + 64, nullptr, 160, w2T + 2 * 65536, nullptr, 64, 1024, 32, Xh, Xl, 3, 0, inp, shifted, maa[2]);
  G(Xh, Xl, 1024, WT_h[2], WT_l[2], 1024, 1024, 1024, v_f, nullptr, 0, 1, nullptr, nullptr, nullptr);
  // g (swish epilogue)
  G(m1h + 128, nullptr, 160, w2T + 4 * 65536, nullptr, 64, 1024, 32, Xh, Xl, 3, 0, inp, shifted, maa[4]);
  G(Xh, Xl, 1024, WT_h[3], WT_l[3], 1024, 1024, 1024, g_f, nullptr, 2, 1, nullptr, nullptr, nullptr);
  // w = exp(-exp(tdh @ tdw2 + time_decay))
  G(tdhh, nullptr, 32, tdw2T, nullptr, 64, 1024, 32, w_f, nullptr, 4, 0, tdec, nullptr, nullptr);

  float* stateOut = (float*)d_out + 4194304 + 4096;
  wkv_k<<<dim3(256), 128, 0, stream>>>(r_f, k_f, v_f, w_f, tf, st0, so_f, stateOut);
  gn_k<<<dim3(1024, 16), 256, 0, stream>>>(so_f, g_f, gsc, gbi, yh, yl);
  // final: (y*g) @ Wo -> d_out
  G(yh, yl, 1024, WT_h[4], WT_l[4], 1024, 1024, 1024, (float*)d_out, nullptr, 0, 1, nullptr, nullptr, nullptr);
  // new_shifted = inputs[-1]
  hipMemcpyAsync((float*)d_out + 4194304, inp + 4096ull * 1023, 4096 * sizeof(float),
                 hipMemcpyDeviceToDevice, stream);
}

// Round 10
// 842.081 us; speedup vs baseline: 1.2459x; 1.0322x over previous
//
#include <hip/hip_runtime.h>

using uint = unsigned int;
using ushort = unsigned short;
using f32x4 = __attribute__((ext_vector_type(4))) float;
using bf16x8 = __attribute__((ext_vector_type(8))) short;

// ---------- helpers ----------
__device__ __forceinline__ ushort f2bf(float x) {
  uint b = __float_as_uint(x);
  return (ushort)((b + 0x7FFFu + ((b >> 16) & 1u)) >> 16);
}
__device__ __forceinline__ float bf2f(ushort u) { return __uint_as_float(((uint)u) << 16); }

__device__ __forceinline__ void gload16(const void* g, void* l) {
  __builtin_amdgcn_global_load_lds((const __attribute__((address_space(1))) void*)g,
                                   (__attribute__((address_space(3))) void*)l, 16, 0, 0);
}

struct __align__(8) U4 { ushort x, y, z, w; };

// ---------- transpose + bf16 split convert: src (R,C) f32 -> out (C rows, ldo cols), zero for r>=R ----------
__device__ __forceinline__ void convT_impl(const float* src, ushort* oh, ushort* ol, int R, int C, int ldo) {
  const int r0 = blockIdx.x * 32, c0 = blockIdx.y * 32;
  if (r0 >= ldo || c0 >= C) return;
  __shared__ float tile[32][33];
  const int tx = threadIdx.x & 31, ty = threadIdx.x >> 5;
#pragma unroll
  for (int j = 0; j < 4; ++j) {
    const int r = r0 + ty + j * 8;
    tile[ty + j * 8][tx] = (r < R) ? src[(size_t)r * C + c0 + tx] : 0.f;
  }
  __syncthreads();
#pragma unroll
  for (int j = 0; j < 4; ++j) {
    const int c = c0 + ty + j * 8;
    const int r = r0 + tx;
    const float v = tile[tx][ty + j * 8];
    const ushort hb = f2bf(v);
    oh[(size_t)c * ldo + r] = hb;
    if (ol) ol[(size_t)c * ldo + r] = f2bf(v - bf2f(hb));
  }
}

struct ConvBig { const float* s[5]; ushort* oh[5]; ushort* ol[5]; };
__global__ void conv_big_k(ConvBig a) {
  const int z = blockIdx.z;
  convT_impl(a.s[z], a.oh[z], a.ol[z], 1024, 1024, 1024);
}

struct ConvSmall { const float* s[8]; ushort* oh[8]; int R[8]; int C[8]; int ldo[8]; };
__global__ void conv_small_k(ConvSmall a) {
  const int z = blockIdx.z;
  convT_impl(a.s[z], a.oh[z], nullptr, a.R[z], a.C[z], a.ldo[z]);
}

// ---------- token-shift mix for xxx = x + (prev - x)*time_maa_x  -> bf16 (hi only) ----------
__global__ void mixx_k(const float* __restrict__ x, const float* __restrict__ sh,
                       const float* __restrict__ maa, ushort* __restrict__ xh) {
  const size_t i = ((size_t)blockIdx.x * 256 + threadIdx.x) * 4;
  const size_t row = i >> 10;
  const int col = (int)(i & 1023);
  const float4 xv = *(const float4*)(x + i);
  const float4 pv = (row < 4) ? *(const float4*)(sh + i) : *(const float4*)(x + i - 4096);
  const float4 mv = *(const float4*)(maa + col);
  U4 o;
  o.x = f2bf(xv.x + (pv.x - xv.x) * mv.x);
  o.y = f2bf(xv.y + (pv.y - xv.y) * mv.y);
  o.z = f2bf(xv.z + (pv.z - xv.z) * mv.z);
  o.w = f2bf(xv.w + (pv.w - xv.w) * mv.w);
  *(U4*)(xh + i) = o;
}

// ---------- GEMM: C(M=4096, N) = A(M,K) @ B(K,N), A row-major bf16 h/l, B given as B^T (N,K) bf16 h/l ----------
struct GemmP {
  const ushort *Ah, *Al, *Bh, *Bl;
  void *out0, *out1;
  const float *aux0, *aux1, *aux2;
  int lda, ldb, M, N, K, epi, split;
};

__device__ __forceinline__ bf16x8 fragld(const ushort* smbase, int byteOff, int rb, int ks, int l) {
  const int row = rb + (l & 15);
  const int kb = (ks << 6) | (((l >> 4) & 3) << 4);
  const int off = byteOff + row * 128 + (kb ^ ((row & 7) << 4));
  return *(const bf16x8*)((const char*)smbase + off);
}

__global__ __launch_bounds__(256, 2) void gemm_k(GemmP p) {
  __shared__ __align__(16) ushort sm[32768];  // 64KB: Ah | Bh | Al | Bl, 16KB each
  const int t = threadIdx.x;
  const int l = t & 63, wid = t >> 6;
  const int wm = wid >> 1, wn = wid & 1;
  const int bm = blockIdx.x, bn = blockIdx.y;

  f32x4 acc[4][4];
#pragma unroll
  for (int i = 0; i < 4; ++i)
#pragma unroll
    for (int j = 0; j < 4; ++j) acc[i][j] = (f32x4){0.f, 0.f, 0.f, 0.f};

  const int srow = t >> 3;         // 0..31
  const int skb = (t & 7) << 4;    // 0..112
  const int KT = (p.K + 63) >> 6;

  for (int kt = 0; kt < KT; ++kt) {
    const int k0 = kt << 6;
    __syncthreads();
#pragma unroll
    for (int j = 0; j < 4; ++j) {
      const int row = srow + j * 32;
      const int srcK = k0 + ((skb ^ ((row & 7) << 4)) >> 1);
      gload16(p.Ah + (size_t)(bm * 128 + row) * p.lda + srcK, (char*)sm + row * 128 + skb);
      gload16(p.Bh + (size_t)(bn * 128 + row) * p.ldb + srcK, (char*)sm + 16384 + row * 128 + skb);
    }
    if (p.split) {
#pragma unroll
      for (int j = 0; j < 4; ++j) {
        const int row = srow + j * 32;
        const int srcK = k0 + ((skb ^ ((row & 7) << 4)) >> 1);
        gload16(p.Al + (size_t)(bm * 128 + row) * p.lda + srcK, (char*)sm + 32768 + row * 128 + skb);
        gload16(p.Bl + (size_t)(bn * 128 + row) * p.ldb + srcK, (char*)sm + 49152 + row * 128 + skb);
      }
    }
    __syncthreads();
#pragma unroll
    for (int ks = 0; ks < 2; ++ks) {
      bf16x8 ah[4], bh[4];
#pragma unroll
      for (int f = 0; f < 4; ++f) {
        ah[f] = fragld(sm, 0, wm * 64 + f * 16, ks, l);
        bh[f] = fragld(sm, 16384, wn * 64 + f * 16, ks, l);
      }
      if (p.split) {
        bf16x8 al[4], bl[4];
#pragma unroll
        for (int f = 0; f < 4; ++f) {
          al[f] = fragld(sm, 32768, wm * 64 + f * 16, ks, l);
          bl[f] = fragld(sm, 49152, wn * 64 + f * 16, ks, l);
        }
#pragma unroll
        for (int mf = 0; mf < 4; ++mf)
#pragma unroll
          for (int nf = 0; nf < 4; ++nf) {
            acc[mf][nf] = __builtin_amdgcn_mfma_f32_16x16x32_bf16(ah[mf], bh[nf], acc[mf][nf], 0, 0, 0);
            acc[mf][nf] = __builtin_amdgcn_mfma_f32_16x16x32_bf16(ah[mf], bl[nf], acc[mf][nf], 0, 0, 0);
            acc[mf][nf] = __builtin_amdgcn_mfma_f32_16x16x32_bf16(al[mf], bh[nf], acc[mf][nf], 0, 0, 0);
          }
      } else {
#pragma unroll
        for (int mf = 0; mf < 4; ++mf)
#pragma unroll
          for (int nf = 0; nf < 4; ++nf)
            acc[mf][nf] = __builtin_amdgcn_mfma_f32_16x16x32_bf16(ah[mf], bh[nf], acc[mf][nf], 0, 0, 0);
      }
    }
  }

  const int rb0 = bm * 128 + wm * 64 + ((l >> 4) << 2);
  const int cb0 = bn * 128 + wn * 64 + (l & 15);
#pragma unroll
  for (int mf = 0; mf < 4; ++mf) {
#pragma unroll
    for (int nf = 0; nf < 4; ++nf) {
      const int col = cb0 + nf * 16;
      if (col >= p.N) continue;
#pragma unroll
      for (int jj = 0; jj < 4; ++jj) {
        const int row = rb0 + mf * 16 + jj;
        const float v = acc[mf][nf][jj];
        const size_t o = (size_t)row * p.N + col;
        if (p.epi == 0) {
          ((float*)p.out0)[o] = v;
        } else if (p.epi == 1) {           // tanh -> bf16 (hi)
          ((ushort*)p.out0)[o] = f2bf(tanhf(v));
        } else if (p.epi == 2) {           // swish -> f32
          ((float*)p.out0)[o] = v / (1.f + expf(-v));
        } else if (p.epi == 3) {           // token-shift mix -> bf16 hi/lo
          const float x = p.aux0[(size_t)row * 1024 + col];
          const float pv = (row < 4) ? p.aux1[(size_t)row * 1024 + col]
                                     : p.aux0[(size_t)(row - 4) * 1024 + col];
          const float xi = x + (pv - x) * (p.aux2[col] + v);
          const ushort hb = f2bf(xi);
          ((ushort*)p.out0)[o] = hb;
          ((ushort*)p.out1)[o] = f2bf(xi - bf2f(hb));
        } else {                            // epi==4: w = exp(-exp(acc + time_decay[c])) -> f32
          ((float*)p.out0)[o] = expf(-expf(v + p.aux0[col]));
        }
      }
    }
  }
}

// ---------- WKV6 scan v4: register-state + explicit 2-stage software pipeline ----------
// R9 post-mortem: v3 was DS-LATENCY-bound (612 cyc/step, VALUBusy 11%, 1 wave/SIMD, no TLP).
// v4 keeps the v3 decomposition (lane = 8 n-slices x 8 m, 3 shuffles) but pipelines in source:
//  - iteration t prefetches t+1's 7 LDS operands into registers first (latency hidden under t's FMAs)
//  - the 3-shuffle reduce of step t-1 is interleaved between t's independent FMA groups
//  - first (garbage) store goes to a dummy ws sink -> branchless loop; epilogue flushes last step.
#define TCH 32
#define NCH (1024 / TCH)
__global__ __launch_bounds__(128) void wkv_k(const float* __restrict__ rf, const float* __restrict__ kf,
                                             const float* __restrict__ vf, const float* __restrict__ wf,
                                             const float* __restrict__ tf, const float* __restrict__ st0,
                                             float* __restrict__ so, float* __restrict__ stO,
                                             float* __restrict__ dsink) {
  __shared__ __align__(16) float sv[2][TCH][16], sr[2][TCH][64], sk[2][TCH][64], sw[2][TCH][64];
  const int tl = threadIdx.x;          // 0..127
  const int l = tl & 63, wid = tl >> 6;
  const int bh = blockIdx.x & 63;      // mg-siblings adjacent mod 64 -> same XCD
  const int mg = blockIdx.x >> 6;      // 0..3 (16 m's each)
  const int b = bh >> 4, h = bh & 15;
  const int slice = l & 7;             // n-slice: n in [slice*8, slice*8+8)
  const int ml = (wid << 3) + (l >> 3);  // m within block 0..15
  const int m = (mg << 4) + ml;        // global m 0..63
  const int n0 = slice << 3;
  const size_t bOff = (size_t)b * 1024 + h * 64;

  float s[8], u[8];
  const size_t sBase = ((size_t)bh * 64 + n0) * 64 + m;
#pragma unroll
  for (int j = 0; j < 8; ++j) s[j] = st0[sBase + (size_t)j * 64];
#pragma unroll
  for (int j = 0; j < 8; ++j) u[j] = tf[h * 64 + n0 + j];

  const int tq = tl >> 4;              // 0..7
  const int c16 = (tl & 15) << 2;      // float offset 0..60
  const int tv = tl >> 2, jv = (tl & 3) << 2;

  auto stage = [&](int bufS, int c) {
    const size_t g0 = (size_t)(c * TCH) * 4096 + bOff;
#pragma unroll
    for (int q = 0; q < 4; ++q) {
      const int trow = q * 8 + tq;
      const size_t ga = g0 + (size_t)trow * 4096 + c16;
      gload16(rf + ga, &sr[bufS][trow][c16]);
      gload16(kf + ga, &sk[bufS][trow][c16]);
      gload16(wf + ga, &sw[bufS][trow][c16]);
    }
    gload16(vf + g0 + (size_t)tv * 4096 + (mg << 4) + jv, &sv[bufS][tv][jv]);
  };

  float prp = 0.f;                     // pending (previous-step) partial, reduced one step late
  float* oPrev = dsink;                // first flush lands in the sink
  float* oCur = so + bOff + m;

  stage(0, 0);
  int buf = 0;
  for (int c = 0; c < NCH; ++c) {
    __syncthreads();                   // chunk c resident in buf
    if (c + 1 < NCH) stage(buf ^ 1, c + 1);
    // operands for step 0 of this chunk
    float4 ra = *(const float4*)&sr[buf][0][n0];
    float4 rb = *(const float4*)&sr[buf][0][n0 + 4];
    float4 ka = *(const float4*)&sk[buf][0][n0];
    float4 kb = *(const float4*)&sk[buf][0][n0 + 4];
    float4 wa = *(const float4*)&sw[buf][0][n0];
    float4 wb = *(const float4*)&sw[buf][0][n0 + 4];
    float vm = sv[buf][0][ml];
#pragma unroll 8
    for (int t = 0; t < TCH; ++t) {
      const int tn = (t + 1 < TCH) ? t + 1 : TCH - 1;   // uniform select, no branch
      // prefetch step t+1 (consumed next iteration; latency hidden under this step's FMAs)
      const float4 nra = *(const float4*)&sr[buf][tn][n0];
      const float4 nrb = *(const float4*)&sr[buf][tn][n0 + 4];
      const float4 nka = *(const float4*)&sk[buf][tn][n0];
      const float4 nkb = *(const float4*)&sk[buf][tn][n0 + 4];
      const float4 nwa = *(const float4*)&sw[buf][tn][n0];
      const float4 nwb = *(const float4*)&sw[buf][tn][n0 + 4];
      const float nvm = sv[buf][tn][ml];
      // interleave: reduce of prp (step t-1) between this step's independent FMA groups
      float q1 = __shfl_xor(prp, 1);
      const float kv0 = ka.x * vm, kv1 = ka.y * vm, kv2 = ka.z * vm, kv3 = ka.w * vm;
      const float kv4 = kb.x * vm, kv5 = kb.y * vm, kv6 = kb.z * vm, kv7 = kb.w * vm;
      prp += q1;
      float q2 = __shfl_xor(prp, 2);
      float pA = ra.x * fmaf(u[0], kv0, s[0]);
      pA = fmaf(ra.y, fmaf(u[1], kv1, s[1]), pA);
      float pB = ra.z * fmaf(u[2], kv2, s[2]);
      pB = fmaf(ra.w, fmaf(u[3], kv3, s[3]), pB);
      prp += q2;
      float q3 = __shfl_xor(prp, 4);
      float pC = rb.x * fmaf(u[4], kv4, s[4]);
      pC = fmaf(rb.y, fmaf(u[5], kv5, s[5]), pC);
      float pD = rb.z * fmaf(u[6], kv6, s[6]);
      pD = fmaf(rb.w, fmaf(u[7], kv7, s[7]), pD);
      prp += q3;
      if (slice == 0) *oPrev = prp;
      s[0] = fmaf(wa.x, s[0], kv0);
      s[1] = fmaf(wa.y, s[1], kv1);
      s[2] = fmaf(wa.z, s[2], kv2);
      s[3] = fmaf(wa.w, s[3], kv3);
      s[4] = fmaf(wb.x, s[4], kv4);
      s[5] = fmaf(wb.y, s[5], kv5);
      s[6] = fmaf(wb.z, s[6], kv6);
      s[7] = fmaf(wb.w, s[7], kv7);
      prp = (pA + pB) + (pC + pD);
      oPrev = oCur;
      oCur += 4096;
      ra = nra; rb = nrb; ka = nka; kb = nkb; wa = nwa; wb = nwb; vm = nvm;  // renamed by unroll
    }
    buf ^= 1;
  }
  // flush last step
  prp += __shfl_xor(prp, 1);
  prp += __shfl_xor(prp, 2);
  prp += __shfl_xor(prp, 4);
  if (slice == 0) *oPrev = prp;
#pragma unroll
  for (int j = 0; j < 8; ++j) stO[sBase + (size_t)j * 64] = s[j];
}

// ---------- GroupNorm over (B, N) per (t,h), fused *g gate, -> bf16 hi/lo ----------
__global__ __launch_bounds__(256) void gn_k(const float* __restrict__ so, const float* __restrict__ gf,
                                            const float* __restrict__ sc, const float* __restrict__ bi,
                                            ushort* __restrict__ yh, ushort* __restrict__ yl) {
  const int tdx = threadIdx.x;
  const int b = tdx >> 6, n = tdx & 63;
  const int t = blockIdx.x, h = blockIdx.y;
  const size_t idx = (size_t)t * 4096 + (size_t)b * 1024 + h * 64 + n;
  const float v = so[idx];
  float s = v, s2 = v * v;
#pragma unroll
  for (int off = 1; off < 64; off <<= 1) {
    s += __shfl_xor(s, off);
    s2 += __shfl_xor(s2, off);
  }
  __shared__ float ps[4], ps2[4];
  if ((tdx & 63) == 0) { ps[b] = s; ps2[b] = s2; }
  __syncthreads();
  const float S = ps[0] + ps[1] + ps[2] + ps[3];
  const float S2 = ps2[0] + ps2[1] + ps2[2] + ps2[3];
  const float mean = S * (1.f / 256.f);
  const float var = S2 * (1.f / 256.f) - mean * mean;
  const float inv = rsqrtf(var + 6.4e-4f);  // eps = 1e-5 * 8^2
  const int c = h * 64 + n;
  float y = (v - mean) * inv * sc[c] + bi[c];
  y *= gf[idx];
  const ushort hb = f2bf(y);
  yh[idx] = hb;
  yl[idx] = f2bf(y - bf2f(hb));
}

// ---------- host ----------
extern "C" void kernel_launch(void* const* d_in, const int* in_sizes, int n_in,
                              void* d_out, int out_size, void* d_ws, size_t ws_size,
                              hipStream_t stream) {
  const float* inp = (const float*)d_in[0];
  const float* shifted = (const float*)d_in[1];
  const float* st0 = (const float*)d_in[2];
  const float* maa_x = (const float*)d_in[3];
  const float* maa[5] = {(const float*)d_in[4], (const float*)d_in[5], (const float*)d_in[6],
                         (const float*)d_in[7], (const float*)d_in[8]};  // w,k,v,r,g
  const float* w1 = (const float*)d_in[9];
  const float* w2 = (const float*)d_in[10];
  const float* W[5] = {(const float*)d_in[11], (const float*)d_in[12], (const float*)d_in[13],
                       (const float*)d_in[14], (const float*)d_in[15]};  // Wr Wk Wv Wg Wo
  const float* tdw1 = (const float*)d_in[16];
  const float* tdw2 = (const float*)d_in[17];
  const float* tdec = (const float*)d_in[18];
  const float* tf = (const float*)d_in[19];
  const float* gsc = (const float*)d_in[20];
  const float* gbi = (const float*)d_in[21];
  (void)in_sizes; (void)n_in; (void)out_size; (void)ws_size;

  char* ws = (char*)d_ws;
  size_t cur = 0;
  auto alloc = [&](size_t bytes) { char* r = ws + cur; cur += (bytes + 255) & ~(size_t)255; return r; };
  ushort *WT_h[5], *WT_l[5];
  for (int i = 0; i < 5; ++i) {
    WT_h[i] = (ushort*)alloc(1024 * 1024 * 2);
    WT_l[i] = (ushort*)alloc(1024 * 1024 * 2);
  }
  ushort* w1T = (ushort*)alloc(256 * 1024 * 2);       // N-pad to 256 rows
  ushort* tdw1T = (ushort*)alloc(128 * 1024 * 2);     // N-pad to 128 rows
  ushort* tdw2T = (ushort*)alloc(1024 * 64 * 2);      // K-pad to 64 (zero-filled)
  ushort* w2T = (ushort*)alloc(5 * 1024 * 64 * 2);    // K-pad to 64 (zero-filled)
  ushort* xxh = (ushort*)alloc(4096ull * 1024 * 2);
  ushort* m1h = (ushort*)alloc(4096ull * 160 * 2 + 256);  // +pad: K-tile overread on last row
  ushort* Xh = (ushort*)alloc(4096ull * 1024 * 2);
  ushort* Xl = (ushort*)alloc(4096ull * 1024 * 2);
  ushort* tdhh = (ushort*)alloc(4096ull * 32 * 2 + 256);
  float* r_f = (float*)alloc(16777216);
  float* k_f = (float*)alloc(16777216);
  float* v_f = (float*)alloc(16777216);
  float* w_f = (float*)alloc(16777216);
  float* g_f = (float*)alloc(16777216);
  float* so_f = (float*)alloc(16777216);
  ushort* yh = (ushort*)alloc(8388608);
  ushort* yl = (ushort*)alloc(8388608);
  float* dsink = (float*)alloc(256);   // garbage sink for wkv's first (pipeline-fill) store

  ConvBig cb;
  for (int i = 0; i < 5; ++i) { cb.s[i] = W[i]; cb.oh[i] = WT_h[i]; cb.ol[i] = WT_l[i]; }
  conv_big_k<<<dim3(32, 32, 5), 256, 0, stream>>>(cb);
  ConvSmall cs;
  cs.s[0] = w1;   cs.oh[0] = w1T;   cs.R[0] = 1024; cs.C[0] = 160;  cs.ldo[0] = 1024;
  cs.s[1] = tdw1; cs.oh[1] = tdw1T; cs.R[1] = 1024; cs.C[1] = 32;   cs.ldo[1] = 1024;
  cs.s[2] = tdw2; cs.oh[2] = tdw2T; cs.R[2] = 32;   cs.C[2] = 1024; cs.ldo[2] = 64;
  for (int i = 0; i < 5; ++i) {
    cs.s[3 + i] = w2 + (size_t)i * 32 * 1024;
    cs.oh[3 + i] = w2T + (size_t)i * 1024 * 64;
    cs.R[3 + i] = 32; cs.C[3 + i] = 1024; cs.ldo[3 + i] = 64;
  }
  conv_small_k<<<dim3(32, 32, 8), 256, 0, stream>>>(cs);

  mixx_k<<<dim3(4096), 256, 0, stream>>>(inp, shifted, maa_x, xxh);

  auto G = [&](const ushort* Ah, const ushort* Al, int lda, const ushort* Bh, const ushort* Bl, int ldb,
               int N, int K, void* out0, void* out1, int epi, int split,
               const float* a0, const float* a1, const float* a2) {
    GemmP p{Ah, Al, Bh, Bl, out0, out1, a0, a1, a2, lda, ldb, 4096, N, K, epi, split};
    gemm_k<<<dim3(32, (N + 127) / 128), 256, 0, stream>>>(p);
  };

  // m1 = tanh(xxx @ W1)   (4096 x 160)
  G(xxh, nullptr, 1024, w1T, nullptr, 1024, 160, 1024, m1h, nullptr, 1, 0, nullptr, nullptr, nullptr);
  // gate i (order w,k,v,r,g): Xi = x + (prev-x)*(maa_i + m1[:,32i:+32] @ w2[i]) -> bf16 hi/lo
  G(m1h + 0, nullptr, 160, w2T + 0 * 65536, nullptr, 64, 1024, 32, Xh, Xl, 3, 0, inp, shifted, maa[0]);
  G(Xh, nullptr, 1024, tdw1T, nullptr, 1024, 32, 1024, tdhh, nullptr, 1, 0, nullptr, nullptr, nullptr);
  // r
  G(m1h + 96, nullptr, 160, w2T + 3 * 65536, nullptr, 64, 1024, 32, Xh, Xl, 3, 0, inp, shifted, maa[3]);
  G(Xh, Xl, 1024, WT_h[0], WT_l[0], 1024, 1024, 1024, r_f, nullptr, 0, 1, nullptr, nullptr, nullptr);
  // k
  G(m1h + 32, nullptr, 160, w2T + 1 * 65536, nullptr, 64, 1024, 32, Xh, Xl, 3, 0, inp, shifted, maa[1]);
  G(Xh, Xl, 1024, WT_h[1], WT_l[1], 1024, 1024, 1024, k_f, nullptr, 0, 1, nullptr, nullptr, nullptr);
  // v
  G(m1h + 64, nullptr, 160, w2T + 2 * 65536, nullptr, 64, 1024, 32, Xh, Xl, 3, 0, inp, shifted, maa[2]);
  G(Xh, Xl, 1024, WT_h[2], WT_l[2], 1024, 1024, 1024, v_f, nullptr, 0, 1, nullptr, nullptr, nullptr);
  // g (swish epilogue)
  G(m1h + 128, nullptr, 160, w2T + 4 * 65536, nullptr, 64, 1024, 32, Xh, Xl, 3, 0, inp, shifted, maa[4]);
  G(Xh, Xl, 1024, WT_h[3], WT_l[3], 1024, 1024, 1024, g_f, nullptr, 2, 1, nullptr, nullptr, nullptr);
  // w = exp(-exp(tdh @ tdw2 + time_decay))
  G(tdhh, nullptr, 32, tdw2T, nullptr, 64, 1024, 32, w_f, nullptr, 4, 0, tdec, nullptr, nullptr);

  float* stateOut = (float*)d_out + 4194304 + 4096;
  wkv_k<<<dim3(256), 128, 0, stream>>>(r_f, k_f, v_f, w_f, tf, st0, so_f, stateOut, dsink);
  gn_k<<<dim3(1024, 16), 256, 0, stream>>>(so_f, g_f, gsc, gbi, yh, yl);
  // final: (y*g) @ Wo -> d_out
  G(yh, yl, 1024, WT_h[4], WT_l[4], 1024, 1024, 1024, (float*)d_out, nullptr, 0, 1, nullptr, nullptr, nullptr);
  // new_shifted = inputs[-1]
  hipMemcpyAsync((float*)d_out + 4194304, inp + 4096ull * 1023, 4096 * sizeof(float),
                 hipMemcpyDeviceToDevice, stream);
}